// Round 2
// baseline (1391.013 us; speedup 1.0000x reference)
//
#include <hip/hip_runtime.h>

// Fused Edge2Node: per-edge projection relu(x@W+b) + atomic scatter-mean into
// src/dst accumulators, then a combine kernel producing 0.5*(mean_src+mean_dst).
//
// Decomposition: one WAVE per edge (grid-stride). Lane j owns output column j:
//   - W column j preloaded into 64 VGPRs (w[k] = W[k*64+j]); bias[j] in 1 VGPR.
//   - edge id forced wave-uniform (readfirstlane) so the x-row loads have a
//     wave-uniform address -> SMEM s_load_dwordx4 (x is const __restrict__, no
//     aliasing with the atomic stores), feeding v_fmac's SGPR operand slot.
//   - the per-edge scatter is ONE global_atomic_add per target: 64 lanes cover
//     the contiguous 64-float node row = fully-coalesced 256B atomic burst.

__global__ __launch_bounds__(256, 4) void edge_scatter_kernel(
    const float* __restrict__ x,        // [E,64]
    const int*   __restrict__ src,      // [E]
    const int*   __restrict__ dst,      // [E]
    const float* __restrict__ W,        // [64,64] row-major (k, j)
    const float* __restrict__ bias,     // [64]
    float* __restrict__ sum_src,        // [N,64]
    float* __restrict__ sum_dst,        // [N,64]
    float* __restrict__ cnt_src,        // [N]
    float* __restrict__ cnt_dst,        // [N]
    int E)
{
    const int lane          = threadIdx.x & 63;
    const int wave_in_blk   = threadIdx.x >> 6;
    const int waves_per_blk = blockDim.x >> 6;
    const int gwave  = blockIdx.x * waves_per_blk + wave_in_blk;
    const int nwaves = gridDim.x * waves_per_blk;

    // Preload W column `lane` (coalesced: lane j reads W[k*64+j]).
    float w[64];
#pragma unroll
    for (int k = 0; k < 64; ++k) w[k] = W[k * 64 + lane];
    const float bj = bias[lane];

    for (int e = gwave; e < E; e += nwaves) {
        const int eu = __builtin_amdgcn_readfirstlane(e);   // wave-uniform edge id
        const int s = src[eu];          // uniform -> scalar load
        const int d = dst[eu];
        const float4* __restrict__ xr4 =
            (const float4*)(x + (size_t)eu * 64);           // uniform base

        // 4-way split accumulators break the fmac dependency chain; float4
        // loads keep the uniform-address path wide (s_load_dwordx4).
        float a0 = bj, a1 = 0.0f, a2 = 0.0f, a3 = 0.0f;
#pragma unroll
        for (int k4 = 0; k4 < 16; ++k4) {
            const float4 v = xr4[k4];
            a0 = fmaf(v.x, w[4 * k4 + 0], a0);
            a1 = fmaf(v.y, w[4 * k4 + 1], a1);
            a2 = fmaf(v.z, w[4 * k4 + 2], a2);
            a3 = fmaf(v.w, w[4 * k4 + 3], a3);
        }
        const float h = fmaxf((a0 + a1) + (a2 + a3), 0.0f);

        // Coalesced 256B atomic bursts: lanes 0..63 cover one node row.
        atomicAdd(sum_src + (size_t)s * 64 + lane, h);
        atomicAdd(sum_dst + (size_t)d * 64 + lane, h);
        if (lane == 0) {
            atomicAdd(cnt_src + s, 1.0f);
            atomicAdd(cnt_dst + d, 1.0f);
        }
    }
}

__global__ __launch_bounds__(256) void combine_kernel(
    const float4* __restrict__ sum_src4,
    const float4* __restrict__ sum_dst4,
    const float*  __restrict__ cnt_src,
    const float*  __restrict__ cnt_dst,
    float4* __restrict__ out4,
    int total4)                          // N*16 float4s
{
    int i = blockIdx.x * blockDim.x + threadIdx.x;
    if (i >= total4) return;
    int n = i >> 4;                      // 16 float4 per node row
    float rs = 0.5f / fmaxf(cnt_src[n], 1.0f);
    float rd = 0.5f / fmaxf(cnt_dst[n], 1.0f);
    float4 a = sum_src4[i];
    float4 b = sum_dst4[i];
    float4 o;
    o.x = a.x * rs + b.x * rd;
    o.y = a.y * rs + b.y * rd;
    o.z = a.z * rs + b.z * rd;
    o.w = a.w * rs + b.w * rd;
    out4[i] = o;
}

extern "C" void kernel_launch(void* const* d_in, const int* in_sizes, int n_in,
                              void* d_out, int out_size, void* d_ws, size_t ws_size,
                              hipStream_t stream)
{
    const float* x  = (const float*)d_in[0];   // [E,64]
    const int*   ei = (const int*)d_in[1];     // [2,E]
    // d_in[2] = num_nodes (device scalar) — N derived from out_size instead.
    const float* W  = (const float*)d_in[3];   // [64,64]
    const float* b  = (const float*)d_in[4];   // [64]

    const int E = in_sizes[0] / 64;
    const int N = out_size / 64;

    float* sum_src = (float*)d_ws;
    float* sum_dst = sum_src + (size_t)N * 64;
    float* cnt_src = sum_dst + (size_t)N * 64;
    float* cnt_dst = cnt_src + N;

    // Zero sums + counts (ws is re-poisoned to 0xAA before every timed call,
    // so this must run every launch; hipMemsetAsync is graph-capturable).
    size_t zero_bytes = ((size_t)N * 128 + 2 * (size_t)N) * sizeof(float);
    hipMemsetAsync(d_ws, 0, zero_bytes, stream);

    const int* srcp = ei;
    const int* dstp = ei + E;

    edge_scatter_kernel<<<1280, 256, 0, stream>>>(
        x, srcp, dstp, W, b, sum_src, sum_dst, cnt_src, cnt_dst, E);

    const int total4 = (N * 64) / 4;
    combine_kernel<<<(total4 + 255) / 256, 256, 0, stream>>>(
        (const float4*)sum_src, (const float4*)sum_dst, cnt_src, cnt_dst,
        (float4*)d_out, total4);
}